// Round 3
// baseline (99.475 us; speedup 1.0000x reference)
//
#include <hip/hip_runtime.h>

#define N_TOK   16384
#define DMODEL  2048
#define N_EXP   16
#define CAP     2048             // 2 * N_TOK / N_EXP
#define CHUNK   64               // one wave per chunk
#define N_CHUNK (N_TOK / CHUNK)  // 256

// ---------------------------------------------------------------------------
// K1: per-token argmax (first-max semantics) + per-chunk expert histogram.
// 256 blocks x 64 threads (1 wave). No LDS: ballots only.
// ---------------------------------------------------------------------------
__global__ void __launch_bounds__(64)
k_hist(const float* __restrict__ score,
       int* __restrict__ eidx,
       float* __restrict__ expert_f,
       int* __restrict__ hist) {
    const int tid = threadIdx.x;       // 0..63 == lane
    const int c   = blockIdx.x;
    const int t   = c * CHUNK + tid;

    const float4* s4 = (const float4*)(score + (size_t)t * N_EXP);
    float4 a = s4[0], b = s4[1], cc = s4[2], d = s4[3];
    float v[16] = {a.x,a.y,a.z,a.w, b.x,b.y,b.z,b.w,
                   cc.x,cc.y,cc.z,cc.w, d.x,d.y,d.z,d.w};
    float best = v[0];
    int bi = 0;
#pragma unroll
    for (int j = 1; j < 16; ++j)
        if (v[j] > best) { best = v[j]; bi = j; }   // strict > keeps first max

    eidx[t] = bi;
    expert_f[t] = (float)bi;

    int cnt = 0;
#pragma unroll
    for (int ex = 0; ex < N_EXP; ++ex) {
        unsigned long long m = __ballot(bi == ex);
        if (tid == ex) cnt = __popcll(m);           // lane ex keeps expert ex's count
    }
    if (tid < N_EXP) hist[c * N_EXP + tid] = cnt;
}

// ---------------------------------------------------------------------------
// K2: per-chunk redundant exclusive scan + rank -> pos/keep/slot_map/count.
// 256 blocks x 64 threads. Each block sums hist (16KB, L2-hot) itself:
// lane layout e = tid&15, g = tid>>4; reduce groups via shfl_xor(16/32).
// ---------------------------------------------------------------------------
__global__ void __launch_bounds__(64)
k_scanpos(const int* __restrict__ eidx,
          const int* __restrict__ hist,
          int* __restrict__ slot_map,
          int* __restrict__ count,
          float* __restrict__ pos_f,
          float* __restrict__ keep_f) {
    const int tid = threadIdx.x;
    const int c   = blockIdx.x;
    const int t   = c * CHUNK + tid;
    const int e   = eidx[t];

    const int eg = tid & 15;
    const int g  = tid >> 4;           // 4 groups of 16 lanes
    int pbase = 0, ptot = 0;
    for (int k = g; k < N_CHUNK; k += 4) {
        const int h = hist[k * N_EXP + eg];
        ptot += h;
        if (k < c) pbase += h;
    }
    pbase += __shfl_xor(pbase, 16); pbase += __shfl_xor(pbase, 32);
    ptot  += __shfl_xor(ptot,  16); ptot  += __shfl_xor(ptot,  32);
    // lane L now holds base/total for expert L&15; lanes 0..15 cover all experts.

    const int base_e = __shfl(pbase, e);            // expert e's base (lane e)

    const unsigned long long below = (1ull << tid) - 1ull;
    int rank = 0;
#pragma unroll
    for (int ex = 0; ex < N_EXP; ++ex) {
        unsigned long long m = __ballot(e == ex);
        if (e == ex) rank = __popcll(m & below);
    }

    const int pos = base_e + rank;
    pos_f[t]  = (float)pos;
    keep_f[t] = (pos < CAP) ? 1.0f : 0.0f;
    if (pos < CAP) slot_map[e * CAP + pos] = t;

    if (c == 0 && tid < N_EXP) count[tid] = ptot;   // lane tid == expert tid
}

// ---------------------------------------------------------------------------
// K3: pure streaming fill. One block per output row; copy or zero.
// Slots [0, count[e]) are dense-filled, so slot_map is never read stale.
// ---------------------------------------------------------------------------
__global__ void __launch_bounds__(256)
k_fill(const float* __restrict__ inputs,
       const int* __restrict__ slot_map,
       const int* __restrict__ count,
       float* __restrict__ dispatched) {
    const int s   = blockIdx.x;          // e*CAP + c
    const int e   = s >> 11;
    const int c   = s & (CAP - 1);
    const int tid = threadIdx.x;
    float4* out4 = (float4*)(dispatched + (size_t)s * DMODEL);
    if (c < count[e]) {
        const int tok = slot_map[s];
        const float4* in4 = (const float4*)(inputs + (size_t)tok * DMODEL);
        out4[tid]       = in4[tid];
        out4[tid + 256] = in4[tid + 256];
    } else {
        const float4 z = {0.f, 0.f, 0.f, 0.f};
        out4[tid]       = z;
        out4[tid + 256] = z;
    }
}

// ---------------------------------------------------------------------------
extern "C" void kernel_launch(void* const* d_in, const int* in_sizes, int n_in,
                              void* d_out, int out_size, void* d_ws, size_t ws_size,
                              hipStream_t stream) {
    const float* inputs = (const float*)d_in[0];
    const float* score  = (const float*)d_in[1];

    float* out        = (float*)d_out;
    float* dispatched = out;                                   // E*CAP*DMODEL
    float* expert_f   = out + (size_t)N_EXP * CAP * DMODEL;    // N_TOK
    float* pos_f      = expert_f + N_TOK;                      // N_TOK
    float* keep_f     = pos_f + N_TOK;                         // N_TOK

    int* eidx     = (int*)d_ws;                    // N_TOK
    int* hist     = eidx + N_TOK;                  // N_CHUNK * N_EXP
    int* slot_map = hist + N_CHUNK * N_EXP;        // N_EXP * CAP
    int* count    = slot_map + N_EXP * CAP;        // N_EXP

    k_hist<<<N_CHUNK, CHUNK, 0, stream>>>(score, eidx, expert_f, hist);
    k_scanpos<<<N_CHUNK, CHUNK, 0, stream>>>(eidx, hist, slot_map, count,
                                             pos_f, keep_f);
    k_fill<<<N_EXP * CAP, 256, 0, stream>>>(inputs, slot_map, count, dispatched);
}